// Round 3
// baseline (928.633 us; speedup 1.0000x reference)
//
#include <hip/hip_runtime.h>
#include <hip/hip_bf16.h>
#include <math.h>

// VEConv fused kernel for MI355X (gfx950).
// h = softplus_b05(rbf@W1+b1)@W2+b2 ; ef = edge_f@W3+b3
// m = new_node[src]*h + ef ; out = segment_sum(m, dst, N)
//
// Strategy: bf16 MFMA (16x16x32) for all GEMMs; weights bf16-transposed +
// XOR-swizzled in LDS; rbf/edge_f A-fragments loaded directly from global;
// fp32 atomicAdd scatter for the segment sum.
// (Round 2 resubmit: rounds 0-1 died on container infra / broker capacity,
//  kernel has never actually run.)

typedef __bf16 bf16x8 __attribute__((ext_vector_type(8)));
typedef float f32x4 __attribute__((ext_vector_type(4)));

#define RBF_DIM 128
#define DIM 64

__global__ __launch_bounds__(256) void veconv_kernel(
    const float* __restrict__ new_node,
    const float* __restrict__ rbf,
    const float* __restrict__ edge_f,
    const int* __restrict__ src,
    const int* __restrict__ dst,
    const float* __restrict__ W1, const float* __restrict__ b1,
    const float* __restrict__ W2, const float* __restrict__ b2,
    const float* __restrict__ W3, const float* __restrict__ b3,
    float* __restrict__ out, int N, int E)
{
    // LDS: w1t 16KB | w2t 8KB | w3t 8KB | act 4 waves x 2KB = 8KB  -> 40KB
    __shared__ __align__(16) unsigned char lds[40960];
    unsigned char* w1t = lds;
    unsigned char* w2t = lds + 16384;
    unsigned char* w3t = lds + 24576;

    const int tid = threadIdx.x;
    const int w   = tid >> 6;      // wave id 0..3
    const int l   = tid & 63;      // lane
    unsigned char* actw = lds + 32768 + (w << 11);   // per-wave [16][64] bf16, swizzled

    // ---- Convert weights fp32 -> bf16, transposed W^T[n][k], swizzle byte ^= (n&7)<<4 ----
    for (int idx = tid; idx < RBF_DIM * DIM; idx += 256) {     // W1: [128][64] row-major
        int k = idx >> 6, n = idx & 63;
        unsigned off = ((((unsigned)n) << 8) + (((unsigned)k) << 1)) ^ (((unsigned)(n & 7)) << 4);
        *(__bf16*)(w1t + off) = (__bf16)W1[idx];
    }
    for (int idx = tid; idx < DIM * DIM; idx += 256) {         // W2,W3: [64][64]
        int k = idx >> 6, n = idx & 63;
        unsigned off = ((((unsigned)n) << 7) + (((unsigned)k) << 1)) ^ (((unsigned)(n & 7)) << 4);
        *(__bf16*)(w2t + off) = (__bf16)W2[idx];
        *(__bf16*)(w3t + off) = (__bf16)W3[idx];
    }
    __syncthreads();

    const int l15 = l & 15;
    const int q   = l >> 4;
    const unsigned sw = ((unsigned)(l & 7)) << 4;   // == (n&7)<<4 and (row&7)<<4 for our n,row

    float b1v[4], b2v[4], b3v[4];
    #pragma unroll
    for (int nt = 0; nt < 4; ++nt) {
        b1v[nt] = b1[l15 + (nt << 4)];
        b2v[nt] = b2[l15 + (nt << 4)];
        b3v[nt] = b3[l15 + (nt << 4)];
    }

    const int NT = E >> 6;   // 64 edges per block-iter (E % 64 == 0 for this problem)

    for (int t = blockIdx.x; t < NT; t += gridDim.x) {
        const int ebase = (t << 6) + (w << 4);   // this wave's 16-edge tile

        // ---- A1 fragments: rbf rows direct from global, cvt to bf16 ----
        const float* rrow = rbf + (size_t)(ebase + l15) * RBF_DIM + (q << 3);
        bf16x8 a1[4];
        #pragma unroll
        for (int kc = 0; kc < 4; ++kc) {
            const float4 u = *(const float4*)(rrow + kc * 32);
            const float4 v = *(const float4*)(rrow + kc * 32 + 4);
            bf16x8 a;
            a[0] = (__bf16)u.x; a[1] = (__bf16)u.y; a[2] = (__bf16)u.z; a[3] = (__bf16)u.w;
            a[4] = (__bf16)v.x; a[5] = (__bf16)v.y; a[6] = (__bf16)v.z; a[7] = (__bf16)v.w;
            a1[kc] = a;
        }

        // ---- L1: T1 = rbf @ W1 ----
        f32x4 acc1[4] = {{0.f,0.f,0.f,0.f},{0.f,0.f,0.f,0.f},{0.f,0.f,0.f,0.f},{0.f,0.f,0.f,0.f}};
        #pragma unroll
        for (int kc = 0; kc < 4; ++kc) {
            #pragma unroll
            for (int nt = 0; nt < 4; ++nt) {
                unsigned off = ((((unsigned)(l15 + (nt << 4))) << 8) + ((unsigned)kc << 6) + ((unsigned)q << 4)) ^ sw;
                bf16x8 bf = *(const bf16x8*)(w1t + off);
                acc1[nt] = __builtin_amdgcn_mfma_f32_16x16x32_bf16(a1[kc], bf, acc1[nt], 0, 0, 0);
            }
        }

        // ---- softplus(beta=0.5, thr=14) + bias, stage act as bf16 in per-wave LDS ----
        #pragma unroll
        for (int nt = 0; nt < 4; ++nt) {
            #pragma unroll
            for (int i = 0; i < 4; ++i) {
                float x = acc1[nt][i] + b1v[nt];
                float z = 0.5f * x;
                float s = (z > 14.0f) ? x : 2.0f * log1pf(__expf(z));
                int e = (q << 2) + i;                 // C-frag row = edge-in-tile
                int d = l15 + (nt << 4);              // C-frag col = dim
                unsigned off = ((((unsigned)e) << 7) + (((unsigned)d) << 1)) ^ (((unsigned)(e & 7)) << 4);
                *(__bf16*)(actw + off) = (__bf16)s;
            }
        }
        __syncthreads();   // cross-op LDS visibility before A2 reads

        // ---- A2 fragments from staged act ----
        bf16x8 a2[2];
        #pragma unroll
        for (int kc = 0; kc < 2; ++kc) {
            unsigned off = ((((unsigned)l15) << 7) + ((unsigned)kc << 6) + ((unsigned)q << 4)) ^ sw;
            a2[kc] = *(const bf16x8*)(actw + off);
        }

        // ---- A3 fragments: edge_f rows direct from global ----
        const float* erow = edge_f + (size_t)(ebase + l15) * DIM + (q << 3);
        bf16x8 a3[2];
        #pragma unroll
        for (int kc = 0; kc < 2; ++kc) {
            const float4 u = *(const float4*)(erow + kc * 32);
            const float4 v = *(const float4*)(erow + kc * 32 + 4);
            bf16x8 a;
            a[0] = (__bf16)u.x; a[1] = (__bf16)u.y; a[2] = (__bf16)u.z; a[3] = (__bf16)u.w;
            a[4] = (__bf16)v.x; a[5] = (__bf16)v.y; a[6] = (__bf16)v.z; a[7] = (__bf16)v.w;
            a3[kc] = a;
        }

        // ---- L2: h = act @ W2 ; L3: ef = edge_f @ W3 ----
        f32x4 acc2[4] = {{0.f,0.f,0.f,0.f},{0.f,0.f,0.f,0.f},{0.f,0.f,0.f,0.f},{0.f,0.f,0.f,0.f}};
        f32x4 acc3[4] = {{0.f,0.f,0.f,0.f},{0.f,0.f,0.f,0.f},{0.f,0.f,0.f,0.f},{0.f,0.f,0.f,0.f}};
        #pragma unroll
        for (int kc = 0; kc < 2; ++kc) {
            #pragma unroll
            for (int nt = 0; nt < 4; ++nt) {
                unsigned boff = ((((unsigned)(l15 + (nt << 4))) << 7) + ((unsigned)kc << 6) + ((unsigned)q << 4)) ^ sw;
                bf16x8 bf2 = *(const bf16x8*)(w2t + boff);
                bf16x8 bf3 = *(const bf16x8*)(w3t + boff);
                acc2[nt] = __builtin_amdgcn_mfma_f32_16x16x32_bf16(a2[kc], bf2, acc2[nt], 0, 0, 0);
                acc3[nt] = __builtin_amdgcn_mfma_f32_16x16x32_bf16(a3[kc], bf3, acc3[nt], 0, 0, 0);
            }
        }

        // ---- gather node rows, combine, atomic scatter-sum ----
        const int4 s4 = *(const int4*)(src + ebase + (q << 2));
        const int4 d4 = *(const int4*)(dst + ebase + (q << 2));
        const int sa[4] = {s4.x, s4.y, s4.z, s4.w};
        const int da[4] = {d4.x, d4.y, d4.z, d4.w};
        #pragma unroll
        for (int i = 0; i < 4; ++i) {
            #pragma unroll
            for (int nt = 0; nt < 4; ++nt) {
                int d = l15 + (nt << 4);
                float nv = new_node[sa[i] * DIM + d];
                float mv = fmaf(nv, acc2[nt][i] + b2v[nt], acc3[nt][i] + b3v[nt]);
                atomicAdd(out + (size_t)da[i] * DIM + d, mv);
            }
        }
    }
}

extern "C" void kernel_launch(void* const* d_in, const int* in_sizes, int n_in,
                              void* d_out, int out_size, void* d_ws, size_t ws_size,
                              hipStream_t stream) {
    const float* new_node = (const float*)d_in[0];
    const float* rbf      = (const float*)d_in[1];
    const float* edge_f   = (const float*)d_in[2];
    const int*   src      = (const int*)d_in[3];
    const int*   dst      = (const int*)d_in[4];
    const float* W1 = (const float*)d_in[5];
    const float* b1 = (const float*)d_in[6];
    const float* W2 = (const float*)d_in[7];
    const float* b2 = (const float*)d_in[8];
    const float* W3 = (const float*)d_in[9];
    const float* b3 = (const float*)d_in[10];
    float* out = (float*)d_out;

    const int E = in_sizes[3];          // src element count
    const int N = in_sizes[0] / DIM;    // new_node rows

    // harness poisons d_out with 0xAA; atomics need zeros
    hipMemsetAsync(d_out, 0, (size_t)out_size * sizeof(float), stream);

    veconv_kernel<<<dim3(1024), dim3(256), 0, stream>>>(
        new_node, rbf, edge_f, src, dst, W1, b1, W2, b2, W3, b3, out, N, E);
}

// Round 4
// 760.949 us; speedup vs baseline: 1.2204x; 1.2204x over previous
//
#include <hip/hip_runtime.h>
#include <hip/hip_bf16.h>
#include <math.h>

// VEConv fused kernel for MI355X (gfx950).
// h = softplus_b05(rbf@W1+b1)@W2+b2 ; ef = edge_f@W3+b3
// m = new_node[src]*h + ef ; out = segment_sum(m, dst, N)
//
// R4 changes vs R3 (442us, 17% HBM, 2.4% MFMA, 43% VALU, 22.5% occ):
//  1. Mid-loop __syncthreads removed -> per-wave act buffer only needs
//     wave-local lgkmcnt(0) (explicit asm; compiler can't see cross-lane
//     LDS dep). Kills the per-iteration vmcnt(0) drain that serialized the
//     previous iteration's 16 atomics + 4-wave coupling.
//  2. src/dst + new_node gathers hoisted to iteration top -> gather latency
//     hides under the whole MLP (FIFO vmcnt: younger loads don't block).
//  3. softplus: log1pf libcall -> 2*__logf(1+__expf(z)) (abs err <1e-9
//     where it differs; threshold 0.249, measured absmax 0.0625).

typedef __bf16 bf16x8 __attribute__((ext_vector_type(8)));
typedef float f32x4 __attribute__((ext_vector_type(4)));

#define RBF_DIM 128
#define DIM 64

__global__ __launch_bounds__(256) void veconv_kernel(
    const float* __restrict__ new_node,
    const float* __restrict__ rbf,
    const float* __restrict__ edge_f,
    const int* __restrict__ src,
    const int* __restrict__ dst,
    const float* __restrict__ W1, const float* __restrict__ b1,
    const float* __restrict__ W2, const float* __restrict__ b2,
    const float* __restrict__ W3, const float* __restrict__ b3,
    float* __restrict__ out, int N, int E)
{
    // LDS: w1t 16KB | w2t 8KB | w3t 8KB | act 4 waves x 2KB = 8KB  -> 40KB
    __shared__ __align__(16) unsigned char lds[40960];
    unsigned char* w1t = lds;
    unsigned char* w2t = lds + 16384;
    unsigned char* w3t = lds + 24576;

    const int tid = threadIdx.x;
    const int w   = tid >> 6;      // wave id 0..3
    const int l   = tid & 63;      // lane
    unsigned char* actw = lds + 32768 + (w << 11);   // per-wave [16][64] bf16, swizzled

    // ---- Convert weights fp32 -> bf16, transposed W^T[n][k], swizzle byte ^= (n&7)<<4 ----
    for (int idx = tid; idx < RBF_DIM * DIM; idx += 256) {     // W1: [128][64] row-major
        int k = idx >> 6, n = idx & 63;
        unsigned off = ((((unsigned)n) << 8) + (((unsigned)k) << 1)) ^ (((unsigned)(n & 7)) << 4);
        *(__bf16*)(w1t + off) = (__bf16)W1[idx];
    }
    for (int idx = tid; idx < DIM * DIM; idx += 256) {         // W2,W3: [64][64]
        int k = idx >> 6, n = idx & 63;
        unsigned off = ((((unsigned)n) << 7) + (((unsigned)k) << 1)) ^ (((unsigned)(n & 7)) << 4);
        *(__bf16*)(w2t + off) = (__bf16)W2[idx];
        *(__bf16*)(w3t + off) = (__bf16)W3[idx];
    }
    __syncthreads();   // weights visible to all waves (only block barrier in kernel)

    const int l15 = l & 15;
    const int q   = l >> 4;
    const unsigned sw = ((unsigned)(l & 7)) << 4;   // == (n&7)<<4 and (row&7)<<4 for our n,row

    float b1v[4], b2v[4], b3v[4];
    #pragma unroll
    for (int nt = 0; nt < 4; ++nt) {
        b1v[nt] = b1[l15 + (nt << 4)];
        b2v[nt] = b2[l15 + (nt << 4)];
        b3v[nt] = b3[l15 + (nt << 4)];
    }

    const int NT = E >> 6;   // 64 edges per block-iter (E % 64 == 0 here)

    for (int t = blockIdx.x; t < NT; t += gridDim.x) {
        const int ebase = (t << 6) + (w << 4);   // this wave's 16-edge tile

        // ---- issue ALL independent loads first (FIFO vmcnt: each consumer
        //      waits only for its own producer + older ops) ----
        const int4 s4 = *(const int4*)(src + ebase + (q << 2));
        const int4 d4 = *(const int4*)(dst + ebase + (q << 2));

        const float* rrow = rbf + (size_t)(ebase + l15) * RBF_DIM + (q << 3);
        float4 rv[8];
        #pragma unroll
        for (int c = 0; c < 4; ++c) {
            rv[2*c]   = *(const float4*)(rrow + c * 32);
            rv[2*c+1] = *(const float4*)(rrow + c * 32 + 4);
        }
        const float* erow = edge_f + (size_t)(ebase + l15) * DIM + (q << 3);
        float4 ev[4];
        #pragma unroll
        for (int c = 0; c < 2; ++c) {
            ev[2*c]   = *(const float4*)(erow + c * 32);
            ev[2*c+1] = *(const float4*)(erow + c * 32 + 4);
        }

        // gather new_node rows now (waits only s4); latency hides under MLP
        const int sa[4] = {s4.x, s4.y, s4.z, s4.w};
        const int da[4] = {d4.x, d4.y, d4.z, d4.w};
        float nv[4][4];
        #pragma unroll
        for (int i = 0; i < 4; ++i)
            #pragma unroll
            for (int nt = 0; nt < 4; ++nt)
                nv[i][nt] = new_node[(size_t)sa[i] * DIM + l15 + (nt << 4)];

        // ---- A1 fragments (waits rv only) ----
        bf16x8 a1[4];
        #pragma unroll
        for (int c = 0; c < 4; ++c) {
            const float4 u = rv[2*c], v = rv[2*c+1];
            bf16x8 a;
            a[0] = (__bf16)u.x; a[1] = (__bf16)u.y; a[2] = (__bf16)u.z; a[3] = (__bf16)u.w;
            a[4] = (__bf16)v.x; a[5] = (__bf16)v.y; a[6] = (__bf16)v.z; a[7] = (__bf16)v.w;
            a1[c] = a;
        }

        // ---- L1: T1 = rbf @ W1 ----
        f32x4 acc1[4] = {{0.f,0.f,0.f,0.f},{0.f,0.f,0.f,0.f},{0.f,0.f,0.f,0.f},{0.f,0.f,0.f,0.f}};
        #pragma unroll
        for (int kc = 0; kc < 4; ++kc) {
            #pragma unroll
            for (int nt = 0; nt < 4; ++nt) {
                unsigned off = ((((unsigned)(l15 + (nt << 4))) << 8) + ((unsigned)kc << 6) + ((unsigned)q << 4)) ^ sw;
                bf16x8 bf = *(const bf16x8*)(w1t + off);
                acc1[nt] = __builtin_amdgcn_mfma_f32_16x16x32_bf16(a1[kc], bf, acc1[nt], 0, 0, 0);
            }
        }

        // ---- softplus(beta=0.5, thr=14) + bias, stage act as bf16 in per-wave LDS ----
        #pragma unroll
        for (int nt = 0; nt < 4; ++nt) {
            #pragma unroll
            for (int i = 0; i < 4; ++i) {
                float x = acc1[nt][i] + b1v[nt];
                float z = 0.5f * x;
                float ez = __expf(z);
                float s = (z > 14.0f) ? x : 2.0f * __logf(1.0f + ez);
                int e = (q << 2) + i;                 // C-frag row = edge-in-tile
                int d = l15 + (nt << 4);              // C-frag col = dim
                unsigned off = ((((unsigned)e) << 7) + (((unsigned)d) << 1)) ^ (((unsigned)(e & 7)) << 4);
                *(__bf16*)(actw + off) = (__bf16)s;
            }
        }
        // wave-local fence: cross-LANE LDS dep is invisible to the compiler's
        // per-thread alias analysis; lockstep wave only needs lgkmcnt(0).
        asm volatile("s_waitcnt lgkmcnt(0)" ::: "memory");

        // ---- A2 fragments from staged act ----
        bf16x8 a2[2];
        #pragma unroll
        for (int kc = 0; kc < 2; ++kc) {
            unsigned off = ((((unsigned)l15) << 7) + ((unsigned)kc << 6) + ((unsigned)q << 4)) ^ sw;
            a2[kc] = *(const bf16x8*)(actw + off);
        }

        // ---- A3 fragments (waits ev only; nv still in flight) ----
        bf16x8 a3[2];
        #pragma unroll
        for (int c = 0; c < 2; ++c) {
            const float4 u = ev[2*c], v = ev[2*c+1];
            bf16x8 a;
            a[0] = (__bf16)u.x; a[1] = (__bf16)u.y; a[2] = (__bf16)u.z; a[3] = (__bf16)u.w;
            a[4] = (__bf16)v.x; a[5] = (__bf16)v.y; a[6] = (__bf16)v.z; a[7] = (__bf16)v.w;
            a3[c] = a;
        }

        // ---- L2: h = act @ W2 ; L3: ef = edge_f @ W3 ----
        f32x4 acc2[4] = {{0.f,0.f,0.f,0.f},{0.f,0.f,0.f,0.f},{0.f,0.f,0.f,0.f},{0.f,0.f,0.f,0.f}};
        f32x4 acc3[4] = {{0.f,0.f,0.f,0.f},{0.f,0.f,0.f,0.f},{0.f,0.f,0.f,0.f},{0.f,0.f,0.f,0.f}};
        #pragma unroll
        for (int kc = 0; kc < 2; ++kc) {
            #pragma unroll
            for (int nt = 0; nt < 4; ++nt) {
                unsigned boff = ((((unsigned)(l15 + (nt << 4))) << 7) + ((unsigned)kc << 6) + ((unsigned)q << 4)) ^ sw;
                bf16x8 bf2 = *(const bf16x8*)(w2t + boff);
                bf16x8 bf3 = *(const bf16x8*)(w3t + boff);
                acc2[nt] = __builtin_amdgcn_mfma_f32_16x16x32_bf16(a2[kc], bf2, acc2[nt], 0, 0, 0);
                acc3[nt] = __builtin_amdgcn_mfma_f32_16x16x32_bf16(a3[kc], bf3, acc3[nt], 0, 0, 0);
            }
        }

        // ---- combine with prefetched node rows, atomic scatter-sum ----
        #pragma unroll
        for (int i = 0; i < 4; ++i) {
            #pragma unroll
            for (int nt = 0; nt < 4; ++nt) {
                int d = l15 + (nt << 4);
                float mv = fmaf(nv[i][nt], acc2[nt][i] + b2v[nt], acc3[nt][i] + b3v[nt]);
                atomicAdd(out + (size_t)da[i] * DIM + d, mv);
            }
        }
        // no barrier at loop end: atomics stay in flight into next iteration
    }
}

extern "C" void kernel_launch(void* const* d_in, const int* in_sizes, int n_in,
                              void* d_out, int out_size, void* d_ws, size_t ws_size,
                              hipStream_t stream) {
    const float* new_node = (const float*)d_in[0];
    const float* rbf      = (const float*)d_in[1];
    const float* edge_f   = (const float*)d_in[2];
    const int*   src      = (const int*)d_in[3];
    const int*   dst      = (const int*)d_in[4];
    const float* W1 = (const float*)d_in[5];
    const float* b1 = (const float*)d_in[6];
    const float* W2 = (const float*)d_in[7];
    const float* b2 = (const float*)d_in[8];
    const float* W3 = (const float*)d_in[9];
    const float* b3 = (const float*)d_in[10];
    float* out = (float*)d_out;

    const int E = in_sizes[3];          // src element count
    const int N = in_sizes[0] / DIM;    // new_node rows

    // harness poisons d_out with 0xAA; atomics need zeros
    hipMemsetAsync(d_out, 0, (size_t)out_size * sizeof(float), stream);

    veconv_kernel<<<dim3(1024), dim3(256), 0, stream>>>(
        new_node, rbf, edge_f, src, dst, W1, b1, W2, b2, W3, b3, out, N, E);
}